// Round 4
// baseline (404.874 us; speedup 1.0000x reference)
//
#include <hip/hip_runtime.h>

typedef __bf16 bf16_t;
typedef __bf16 bf16x8 __attribute__((ext_vector_type(8)));
typedef float f32x4 __attribute__((ext_vector_type(4)));
typedef unsigned short u16;

// ---------- helpers ----------
__device__ __forceinline__ u16 f2bf(float f) {
  unsigned u = __float_as_uint(f);
  unsigned r = (u + 0x7fffu + ((u >> 16) & 1u)) >> 16;
  return (u16)r;
}

typedef const unsigned __attribute__((address_space(1)))* gptr_t;
typedef unsigned __attribute__((address_space(3)))* lptr_t;

__device__ __forceinline__ void gload_lds16(const u16* g, u16* l) {
  __builtin_amdgcn_global_load_lds((gptr_t)(const void*)g, (lptr_t)(void*)l, 16, 0, 0);
}

#define QSCALE 0.18033688f  // 0.125 * log2(e): folds 1/sqrt(64) and exp->exp2

// ---------- fp32 -> bf16 convert (inputs) ----------
__global__ __launch_bounds__(256) void cvt_f32_bf16(const float* __restrict__ in,
                                                    u16* __restrict__ out, int n4) {
  int i = blockIdx.x * 256 + threadIdx.x;
  if (i >= n4) return;
  float4 v = reinterpret_cast<const float4*>(in)[i];
  ushort4 o;
  o.x = f2bf(v.x); o.y = f2bf(v.y); o.z = f2bf(v.z); o.w = f2bf(v.w);
  reinterpret_cast<ushort4*>(out)[i] = o;
}

// ---------- all 4 weights fp32 -> bf16 in one dispatch ----------
__global__ __launch_bounds__(256) void cvt_w4(const float* __restrict__ Wq,
                                              const float* __restrict__ Wk,
                                              const float* __restrict__ Wv,
                                              const float* __restrict__ Wo,
                                              u16* __restrict__ out) {
  int sel = blockIdx.y;
  const float* in = sel == 0 ? Wq : sel == 1 ? Wk : sel == 2 ? Wv : Wo;
  u16* o = out + sel * 589824;
  int i = blockIdx.x * 256 + threadIdx.x;  // < 147456
  float4 v = reinterpret_cast<const float4*>(in)[i];
  ushort4 ov;
  ov.x = f2bf(v.x); ov.y = f2bf(v.y); ov.z = f2bf(v.z); ov.w = f2bf(v.w);
  reinterpret_cast<ushort4*>(o)[i] = ov;
}

// ---------- adj bit-pack:  [8,1024,1024] int32 -> [8,1024,32] u32 ----------
__global__ __launch_bounds__(256) void pack_adj(const int* __restrict__ adj,
                                                unsigned* __restrict__ bits) {
  unsigned idx = blockIdx.x * 256u + threadIdx.x;   // < 8388608
  int a = adj[idx];
  unsigned long long m = __ballot(a != 0);
  int l = threadIdx.x & 63;
  if ((l & 31) == 0) bits[idx >> 5] = (unsigned)(m >> (l & 32));
}

// ---------- fused QKV GEMM: A[8192,768] x {Wq,Wk,Wv}[768,768]^T + bias ----------
// blockIdx.y in [0,18): 0-5 -> Q (scaled by QSCALE), 6-11 -> K, 12-17 -> V (transposed)
__global__ __launch_bounds__(256) void gemm_qkv(
    const u16* __restrict__ A,
    const u16* __restrict__ Wq, const u16* __restrict__ Wk, const u16* __restrict__ Wv,
    const float* __restrict__ bq, const float* __restrict__ bk, const float* __restrict__ bv,
    u16* __restrict__ Qo, u16* __restrict__ Ko, u16* __restrict__ Vo) {
  __shared__ u16 lds[2][2][128 * 32];
  const int tid = threadIdx.x;
  const int w = tid >> 6, l = tid & 63;
  const int bm = blockIdx.x;
  const int bn = blockIdx.y;
  const int sel = bn / 6;          // 0=Q 1=K 2=V (wave-uniform)
  const int bnl = bn % 6;
  const int lr = l & 15, lg = l >> 4;
  const int wm = w >> 1, wn = w & 1;

  const u16* W = sel == 0 ? Wq : sel == 1 ? Wk : Wv;
  const float* bias = sel == 0 ? bq : sel == 1 ? bk : bv;

  const u16* Abase = A + (bm * 128) * 768;
  const u16* Wbase = W + (bnl * 128) * 768;

  f32x4 acc[4][4];
#pragma unroll
  for (int i = 0; i < 4; ++i)
#pragma unroll
    for (int j = 0; j < 4; ++j) acc[i][j] = f32x4{0.f, 0.f, 0.f, 0.f};

  auto stage = [&](int buf, int k0) {
#pragma unroll
    for (int r = 0; r < 2; ++r) {
      int rowoff = r * 64 + w * 16;                       // wave-uniform
      const u16* ga = Abase + (rowoff + (l >> 2)) * 768 + k0 + (l & 3) * 8;
      const u16* gw = Wbase + (rowoff + (l >> 2)) * 768 + k0 + (l & 3) * 8;
      gload_lds16(ga, &lds[buf][0][rowoff * 32]);
      gload_lds16(gw, &lds[buf][1][rowoff * 32]);
    }
  };

  stage(0, 0);
  int cur = 0;
  for (int kt = 0; kt < 24; ++kt) {
    __syncthreads();
    if (kt < 23) stage(cur ^ 1, (kt + 1) * 32);
    const u16* la = &lds[cur][0][0];
    const u16* lb = &lds[cur][1][0];
    bf16x8 af[4], bw[4];
#pragma unroll
    for (int i = 0; i < 4; ++i)
      af[i] = *(const bf16x8*)&la[(wm * 64 + i * 16 + lr) * 32 + lg * 8];
#pragma unroll
    for (int j = 0; j < 4; ++j)
      bw[j] = *(const bf16x8*)&lb[(wn * 64 + j * 16 + lr) * 32 + lg * 8];
#pragma unroll
    for (int i = 0; i < 4; ++i)
#pragma unroll
      for (int j = 0; j < 4; ++j)
        acc[i][j] = __builtin_amdgcn_mfma_f32_16x16x32_bf16(af[i], bw[j], acc[i][j], 0, 0, 0);
    cur ^= 1;
  }

  const int m0 = bm * 128 + wm * 64;
  const int n0 = bnl * 128 + wn * 64;
#pragma unroll
  for (int i = 0; i < 4; ++i) {
#pragma unroll
    for (int j = 0; j < 4; ++j) {
      int n = n0 + j * 16 + lr;
      float bs = bias[n];
      int h_ = n >> 6, d_ = n & 63;
      if (sel == 2) {
        int m = m0 + i * 16 + lg * 4;
        int b_ = m >> 10, s_ = m & 1023;
        ushort4 o;
        o.x = f2bf(acc[i][j][0] + bs);
        o.y = f2bf(acc[i][j][1] + bs);
        o.z = f2bf(acc[i][j][2] + bs);
        o.w = f2bf(acc[i][j][3] + bs);
        *(ushort4*)&Vo[((b_ * 12 + h_) * 64 + d_) * 1024 + s_] = o;
      } else {
        u16* dst = sel == 0 ? Qo : Ko;
        float sc = sel == 0 ? QSCALE : 1.0f;
#pragma unroll
        for (int r = 0; r < 4; ++r) {
          int m = m0 + i * 16 + lg * 4 + r;
          int b_ = m >> 10, s_ = m & 1023;
          dst[((b_ * 12 + h_) * 1024 + s_) * 64 + d_] = f2bf((acc[i][j][r] + bs) * sc);
        }
      }
    }
  }
}

// ---------- O-proj GEMM: fp32 out = acc + bias + resid ----------
__global__ __launch_bounds__(256) void gemm_o(
    const u16* __restrict__ A, const u16* __restrict__ W,
    const float* __restrict__ bias, const float* __restrict__ resid,
    float* __restrict__ outf) {
  __shared__ u16 lds[2][2][128 * 32];
  const int tid = threadIdx.x;
  const int w = tid >> 6, l = tid & 63;
  const int bm = blockIdx.x, bn = blockIdx.y;
  const int lr = l & 15, lg = l >> 4;
  const int wm = w >> 1, wn = w & 1;

  const u16* Abase = A + (bm * 128) * 768;
  const u16* Wbase = W + (bn * 128) * 768;

  f32x4 acc[4][4];
#pragma unroll
  for (int i = 0; i < 4; ++i)
#pragma unroll
    for (int j = 0; j < 4; ++j) acc[i][j] = f32x4{0.f, 0.f, 0.f, 0.f};

  auto stage = [&](int buf, int k0) {
#pragma unroll
    for (int r = 0; r < 2; ++r) {
      int rowoff = r * 64 + w * 16;
      const u16* ga = Abase + (rowoff + (l >> 2)) * 768 + k0 + (l & 3) * 8;
      const u16* gw = Wbase + (rowoff + (l >> 2)) * 768 + k0 + (l & 3) * 8;
      gload_lds16(ga, &lds[buf][0][rowoff * 32]);
      gload_lds16(gw, &lds[buf][1][rowoff * 32]);
    }
  };

  stage(0, 0);
  int cur = 0;
  for (int kt = 0; kt < 24; ++kt) {
    __syncthreads();
    if (kt < 23) stage(cur ^ 1, (kt + 1) * 32);
    const u16* la = &lds[cur][0][0];
    const u16* lb = &lds[cur][1][0];
    bf16x8 af[4], bw[4];
#pragma unroll
    for (int i = 0; i < 4; ++i)
      af[i] = *(const bf16x8*)&la[(wm * 64 + i * 16 + lr) * 32 + lg * 8];
#pragma unroll
    for (int j = 0; j < 4; ++j)
      bw[j] = *(const bf16x8*)&lb[(wn * 64 + j * 16 + lr) * 32 + lg * 8];
#pragma unroll
    for (int i = 0; i < 4; ++i)
#pragma unroll
      for (int j = 0; j < 4; ++j)
        acc[i][j] = __builtin_amdgcn_mfma_f32_16x16x32_bf16(af[i], bw[j], acc[i][j], 0, 0, 0);
    cur ^= 1;
  }

  const int m0 = bm * 128 + wm * 64;
  const int n0 = bn * 128 + wn * 64;
#pragma unroll
  for (int i = 0; i < 4; ++i) {
#pragma unroll
    for (int j = 0; j < 4; ++j) {
      int n = n0 + j * 16 + lr;
      float bs = bias[n];
#pragma unroll
      for (int r = 0; r < 4; ++r) {
        int m = m0 + i * 16 + lg * 4 + r;
        outf[m * 768 + n] = acc[i][j][r] + bs + resid[m * 768 + n];
      }
    }
  }
}

// ---------- attention, no-max softmax, XCD-local, latency-pipelined ----------
// grid (96, 16): blockIdx.x = bh -> XCD = bh % 8 (96 % 8 == 0 keeps every
// head's K/V on ONE XCD's L2: 12 heads x 256 KB = 3 MB < 4 MB).
// block = 256 thr (4 waves), each wave owns 16 q-rows of one (b,h).
// V loads are issued BEFORE the lgkmcnt barrier so their latency hides under
// the exp + P-LDS roundtrip (the "memory" clobber pins them early).
__global__ __launch_bounds__(256) void attn(
    const u16* __restrict__ Q,   // [96,1024,64]
    const u16* __restrict__ Kt,  // [96,1024,64]
    const u16* __restrict__ VT,  // [96,64,1024]
    const unsigned* __restrict__ bits, // [8,1024,32]
    u16* __restrict__ ctx) {     // [8,1024,768]
  __shared__ u16 plds_all[4][16 * 64];
  const int tid = threadIdx.x;
  const int w = tid >> 6, l = tid & 63;
  const int lr = l & 15, lg = l >> 4;
  const int bh = blockIdx.x;               // 0..95
  const int qt = (blockIdx.y << 2) | w;    // 0..63
  const int b_ = bh / 12, h_ = bh % 12;
  u16* plds = plds_all[w];

  const u16* Qb = Q + (bh * 1024 + qt * 16) * 64;
  const u16* Kb = Kt + bh * 1024 * 64;
  const u16* Vb = VT + bh * 64 * 1024;
  const unsigned* wb = bits + (b_ * 1024 + qt * 16) * 32;

  bf16x8 qa0 = *(const bf16x8*)&Qb[lr * 64 + lg * 8];
  bf16x8 qa1 = *(const bf16x8*)&Qb[lr * 64 + 32 + lg * 8];

  bf16x8 vones;
#pragma unroll
  for (int i = 0; i < 8; ++i) vones[i] = (__bf16)1.0f;

  f32x4 cacc[4];
#pragma unroll
  for (int j = 0; j < 4; ++j) cacc[j] = f32x4{0.f, 0.f, 0.f, 0.f};
  f32x4 lacc = f32x4{0.f, 0.f, 0.f, 0.f};

  for (int kt = 0; kt < 16; ++kt) {
    const int k0 = kt * 64;
    // mask bits: issue early (tiny, L2-resident)
    uint2 mm[4];
#pragma unroll
    for (int r = 0; r < 4; ++r)
      mm[r] = *(const uint2*)&wb[(lg * 4 + r) * 32 + kt * 2];

    // QK^T for this 64-k tile (8 MFMA); K loads batched at top by compiler
    f32x4 s[4];
#pragma unroll
    for (int t = 0; t < 4; ++t) {
      const u16* kp = &Kb[(k0 + t * 16 + lr) * 64 + lg * 8];
      bf16x8 ka = *(const bf16x8*)kp;
      bf16x8 kb2 = *(const bf16x8*)(kp + 32);
      f32x4 z = f32x4{0.f, 0.f, 0.f, 0.f};
      z = __builtin_amdgcn_mfma_f32_16x16x32_bf16(qa0, ka, z, 0, 0, 0);
      z = __builtin_amdgcn_mfma_f32_16x16x32_bf16(qa1, kb2, z, 0, 0, 0);
      s[t] = z;
    }

    // V first half (j=0,1): issue NOW so latency hides under exp + P roundtrip
    const u16* vp0 = &Vb[(0 * 16 + lr) * 1024 + k0 + lg * 8];
    const u16* vp1 = &Vb[(1 * 16 + lr) * 1024 + k0 + lg * 8];
    bf16x8 vv0 = *(const bf16x8*)vp0;
    bf16x8 vv1 = *(const bf16x8*)(vp0 + 32);
    bf16x8 vv2 = *(const bf16x8*)vp1;
    bf16x8 vv3 = *(const bf16x8*)(vp1 + 32);

    // mask + exp2 + bf16 + swizzled LDS write (conflict-free, verified r3)
#pragma unroll
    for (int r = 0; r < 4; ++r) {
      const int q = lg * 4 + r;
      const int sw = (q & 7) << 3;
      unsigned w0 = mm[r].x >> lr;
      unsigned w1 = mm[r].y >> lr;
#pragma unroll
      for (int t = 0; t < 4; ++t) {
        unsigned bit = (t == 0) ? (w0 & 1u)
                     : (t == 1) ? ((w0 >> 16) & 1u)
                     : (t == 2) ? (w1 & 1u)
                                : ((w1 >> 16) & 1u);
        float sv = bit ? s[t][r] : -1e30f;
        float p = exp2f(sv);
        plds[q * 64 + ((t * 16 + lr) ^ sw)] = f2bf(p);
      }
    }

    // V second half (j=2,3): issue before the barrier too
    const u16* vp2 = &Vb[(2 * 16 + lr) * 1024 + k0 + lg * 8];
    const u16* vp3 = &Vb[(3 * 16 + lr) * 1024 + k0 + lg * 8];
    bf16x8 vv4 = *(const bf16x8*)vp2;
    bf16x8 vv5 = *(const bf16x8*)(vp2 + 32);
    bf16x8 vv6 = *(const bf16x8*)vp3;
    bf16x8 vv7 = *(const bf16x8*)(vp3 + 32);

    asm volatile("s_waitcnt lgkmcnt(0)" ::: "memory");
    const int swr = (lr & 7) << 3;
    bf16x8 pa0 = *(const bf16x8*)&plds[lr * 64 + ((lg * 8) ^ swr)];
    bf16x8 pa1 = *(const bf16x8*)&plds[lr * 64 + ((32 + lg * 8) ^ swr)];

    lacc = __builtin_amdgcn_mfma_f32_16x16x32_bf16(pa0, vones, lacc, 0, 0, 0);
    lacc = __builtin_amdgcn_mfma_f32_16x16x32_bf16(pa1, vones, lacc, 0, 0, 0);
    cacc[0] = __builtin_amdgcn_mfma_f32_16x16x32_bf16(pa0, vv0, cacc[0], 0, 0, 0);
    cacc[0] = __builtin_amdgcn_mfma_f32_16x16x32_bf16(pa1, vv1, cacc[0], 0, 0, 0);
    cacc[1] = __builtin_amdgcn_mfma_f32_16x16x32_bf16(pa0, vv2, cacc[1], 0, 0, 0);
    cacc[1] = __builtin_amdgcn_mfma_f32_16x16x32_bf16(pa1, vv3, cacc[1], 0, 0, 0);
    cacc[2] = __builtin_amdgcn_mfma_f32_16x16x32_bf16(pa0, vv4, cacc[2], 0, 0, 0);
    cacc[2] = __builtin_amdgcn_mfma_f32_16x16x32_bf16(pa1, vv5, cacc[2], 0, 0, 0);
    cacc[3] = __builtin_amdgcn_mfma_f32_16x16x32_bf16(pa0, vv6, cacc[3], 0, 0, 0);
    cacc[3] = __builtin_amdgcn_mfma_f32_16x16x32_bf16(pa1, vv7, cacc[3], 0, 0, 0);
  }

  float inv[4];
#pragma unroll
  for (int r = 0; r < 4; ++r) inv[r] = 1.0f / lacc[r];
#pragma unroll
  for (int j = 0; j < 4; ++j) {
#pragma unroll
    for (int r = 0; r < 4; ++r) {
      int q = qt * 16 + lg * 4 + r;
      ctx[(b_ * 1024 + q) * 768 + h_ * 64 + j * 16 + lr] = f2bf(cacc[j][r] * inv[r]);
    }
  }
}

// ---------- LayerNorm: one wave per row of 768 ----------
__global__ __launch_bounds__(256) void layernorm(const float* __restrict__ x,
                                                 const float* __restrict__ gamma,
                                                 const float* __restrict__ beta,
                                                 float* __restrict__ out) {
  int row = blockIdx.x * 4 + (threadIdx.x >> 6);
  int l = threadIdx.x & 63;
  const float4* xr = (const float4*)(x + row * 768);
  float4 v0 = xr[l], v1 = xr[l + 64], v2 = xr[l + 128];
  float s = v0.x + v0.y + v0.z + v0.w + v1.x + v1.y + v1.z + v1.w + v2.x + v2.y + v2.z + v2.w;
#pragma unroll
  for (int d = 1; d < 64; d <<= 1) s += __shfl_xor(s, d);
  float mu = s * (1.0f / 768.0f);
  float q0, q1, q2, vs = 0.f;
  q0 = v0.x - mu; vs += q0 * q0; q0 = v0.y - mu; vs += q0 * q0;
  q0 = v0.z - mu; vs += q0 * q0; q0 = v0.w - mu; vs += q0 * q0;
  q1 = v1.x - mu; vs += q1 * q1; q1 = v1.y - mu; vs += q1 * q1;
  q1 = v1.z - mu; vs += q1 * q1; q1 = v1.w - mu; vs += q1 * q1;
  q2 = v2.x - mu; vs += q2 * q2; q2 = v2.y - mu; vs += q2 * q2;
  q2 = v2.z - mu; vs += q2 * q2; q2 = v2.w - mu; vs += q2 * q2;
#pragma unroll
  for (int d = 1; d < 64; d <<= 1) vs += __shfl_xor(vs, d);
  float rs = rsqrtf(vs * (1.0f / 768.0f) + 1e-5f);
  const float4* g4 = (const float4*)gamma;
  const float4* b4 = (const float4*)beta;
  float4 o;
  float4 g = g4[l], bb = b4[l];
  o.x = (v0.x - mu) * rs * g.x + bb.x; o.y = (v0.y - mu) * rs * g.y + bb.y;
  o.z = (v0.z - mu) * rs * g.z + bb.z; o.w = (v0.w - mu) * rs * g.w + bb.w;
  ((float4*)(out + row * 768))[l] = o;
  g = g4[l + 64]; bb = b4[l + 64];
  o.x = (v1.x - mu) * rs * g.x + bb.x; o.y = (v1.y - mu) * rs * g.y + bb.y;
  o.z = (v1.z - mu) * rs * g.z + bb.z; o.w = (v1.w - mu) * rs * g.w + bb.w;
  ((float4*)(out + row * 768))[l + 64] = o;
  g = g4[l + 128]; bb = b4[l + 128];
  o.x = (v2.x - mu) * rs * g.x + bb.x; o.y = (v2.y - mu) * rs * g.y + bb.y;
  o.z = (v2.z - mu) * rs * g.z + bb.z; o.w = (v2.w - mu) * rs * g.w + bb.w;
  ((float4*)(out + row * 768))[l + 128] = o;
}

// ---------- launch ----------
extern "C" void kernel_launch(void* const* d_in, const int* in_sizes, int n_in,
                              void* d_out, int out_size, void* d_ws, size_t ws_size,
                              hipStream_t stream) {
  (void)in_sizes; (void)n_in; (void)out_size; (void)ws_size;
  const float* inputs = (const float*)d_in[0];
  const int* adj = (const int*)d_in[1];
  const float* Wq = (const float*)d_in[2];
  const float* bq = (const float*)d_in[3];
  const float* Wk = (const float*)d_in[4];
  const float* bk = (const float*)d_in[5];
  const float* Wv = (const float*)d_in[6];
  const float* bv = (const float*)d_in[7];
  const float* Wo = (const float*)d_in[8];
  const float* bo = (const float*)d_in[9];
  const float* gamma = (const float*)d_in[10];
  const float* beta = (const float*)d_in[11];
  float* out = (float*)d_out;
  char* ws = (char*)d_ws;

  // workspace layout (bytes)
  u16* Xbf = (u16*)(ws + 0);              // 12,582,912  (ctx bf16 aliases this later)
  u16* Wqb = (u16*)(ws + 12582912);       //  4 x 1,179,648 contiguous (cvt_w4)
  u16* Wkb = (u16*)(ws + 13762560);
  u16* Wvb = (u16*)(ws + 14942208);
  u16* Wob = (u16*)(ws + 16121856);
  u16* Qb  = (u16*)(ws + 17301504);       // 12,582,912  (x fp32 aliases Q+K later)
  u16* Kb  = (u16*)(ws + 29884416);       // 12,582,912
  u16* VTb = (u16*)(ws + 42467328);       // 12,582,912
  unsigned* bits = (unsigned*)(ws + 55050240); // 1,048,576  -> total 56,098,816
  u16* ctxb = (u16*)(ws + 0);
  float* xbuf = (float*)(ws + 17301504);

  cvt_f32_bf16<<<6144, 256, 0, stream>>>(inputs, Xbf, 1572864);
  cvt_w4<<<dim3(576, 4), 256, 0, stream>>>(Wq, Wk, Wv, Wo, Wqb);
  pack_adj<<<32768, 256, 0, stream>>>(adj, bits);

  gemm_qkv<<<dim3(64, 18), 256, 0, stream>>>(Xbf, Wqb, Wkb, Wvb, bq, bk, bv, Qb, Kb, VTb);

  attn<<<dim3(96, 16), 256, 0, stream>>>(Qb, Kb, VTb, bits, ctxb);

  gemm_o<<<dim3(64, 6), 256, 0, stream>>>(ctxb, Wob, bo, inputs, xbuf);

  layernorm<<<2048, 256, 0, stream>>>(xbuf, gamma, beta, out);
}

// Round 6
// 268.292 us; speedup vs baseline: 1.5091x; 1.5091x over previous
//
#include <hip/hip_runtime.h>

typedef __bf16 bf16_t;
typedef __bf16 bf16x8 __attribute__((ext_vector_type(8)));
typedef float f32x4 __attribute__((ext_vector_type(4)));
typedef unsigned short u16;

// ---------- helpers ----------
__device__ __forceinline__ u16 f2bf(float f) {
  unsigned u = __float_as_uint(f);
  unsigned r = (u + 0x7fffu + ((u >> 16) & 1u)) >> 16;
  return (u16)r;
}

typedef const unsigned __attribute__((address_space(1)))* gptr_t;
typedef unsigned __attribute__((address_space(3)))* lptr_t;

__device__ __forceinline__ void gload_lds16(const u16* g, u16* l) {
  __builtin_amdgcn_global_load_lds((gptr_t)(const void*)g, (lptr_t)(void*)l, 16, 0, 0);
}

#define QSCALE 0.18033688f  // 0.125 * log2(e): folds 1/sqrt(64) and exp->exp2

// ---------- fp32 -> bf16 convert (inputs) ----------
__global__ __launch_bounds__(256) void cvt_f32_bf16(const float* __restrict__ in,
                                                    u16* __restrict__ out, int n4) {
  int i = blockIdx.x * 256 + threadIdx.x;
  if (i >= n4) return;
  float4 v = reinterpret_cast<const float4*>(in)[i];
  ushort4 o;
  o.x = f2bf(v.x); o.y = f2bf(v.y); o.z = f2bf(v.z); o.w = f2bf(v.w);
  reinterpret_cast<ushort4*>(out)[i] = o;
}

// ---------- all 4 weights fp32 -> bf16 in one dispatch ----------
__global__ __launch_bounds__(256) void cvt_w4(const float* __restrict__ Wq,
                                              const float* __restrict__ Wk,
                                              const float* __restrict__ Wv,
                                              const float* __restrict__ Wo,
                                              u16* __restrict__ out) {
  int sel = blockIdx.y;
  const float* in = sel == 0 ? Wq : sel == 1 ? Wk : sel == 2 ? Wv : Wo;
  u16* o = out + sel * 589824;
  int i = blockIdx.x * 256 + threadIdx.x;  // < 147456
  float4 v = reinterpret_cast<const float4*>(in)[i];
  ushort4 ov;
  ov.x = f2bf(v.x); ov.y = f2bf(v.y); ov.z = f2bf(v.z); ov.w = f2bf(v.w);
  reinterpret_cast<ushort4*>(o)[i] = ov;
}

// ---------- adj bit-pack:  [8,1024,1024] int32 -> [8,1024,32] u32 ----------
__global__ __launch_bounds__(256) void pack_adj(const int* __restrict__ adj,
                                                unsigned* __restrict__ bits) {
  unsigned idx = blockIdx.x * 256u + threadIdx.x;   // < 8388608
  int a = adj[idx];
  unsigned long long m = __ballot(a != 0);
  int l = threadIdx.x & 63;
  if ((l & 31) == 0) bits[idx >> 5] = (unsigned)(m >> (l & 32));
}

// ---------- fused QKV GEMM: A[8192,768] x {Wq,Wk,Wv}[768,768]^T + bias ----------
// blockIdx.y in [0,18): 0-5 -> Q (scaled by QSCALE), 6-11 -> K, 12-17 -> V (transposed)
__global__ __launch_bounds__(256) void gemm_qkv(
    const u16* __restrict__ A,
    const u16* __restrict__ Wq, const u16* __restrict__ Wk, const u16* __restrict__ Wv,
    const float* __restrict__ bq, const float* __restrict__ bk, const float* __restrict__ bv,
    u16* __restrict__ Qo, u16* __restrict__ Ko, u16* __restrict__ Vo) {
  __shared__ u16 lds[2][2][128 * 32];
  const int tid = threadIdx.x;
  const int w = tid >> 6, l = tid & 63;
  const int bm = blockIdx.x;
  const int bn = blockIdx.y;
  const int sel = bn / 6;          // 0=Q 1=K 2=V (wave-uniform)
  const int bnl = bn % 6;
  const int lr = l & 15, lg = l >> 4;
  const int wm = w >> 1, wn = w & 1;

  const u16* W = sel == 0 ? Wq : sel == 1 ? Wk : Wv;
  const float* bias = sel == 0 ? bq : sel == 1 ? bk : bv;

  const u16* Abase = A + (bm * 128) * 768;
  const u16* Wbase = W + (bnl * 128) * 768;

  f32x4 acc[4][4];
#pragma unroll
  for (int i = 0; i < 4; ++i)
#pragma unroll
    for (int j = 0; j < 4; ++j) acc[i][j] = f32x4{0.f, 0.f, 0.f, 0.f};

  auto stage = [&](int buf, int k0) {
#pragma unroll
    for (int r = 0; r < 2; ++r) {
      int rowoff = r * 64 + w * 16;                       // wave-uniform
      const u16* ga = Abase + (rowoff + (l >> 2)) * 768 + k0 + (l & 3) * 8;
      const u16* gw = Wbase + (rowoff + (l >> 2)) * 768 + k0 + (l & 3) * 8;
      gload_lds16(ga, &lds[buf][0][rowoff * 32]);
      gload_lds16(gw, &lds[buf][1][rowoff * 32]);
    }
  };

  stage(0, 0);
  int cur = 0;
  for (int kt = 0; kt < 24; ++kt) {
    __syncthreads();
    if (kt < 23) stage(cur ^ 1, (kt + 1) * 32);
    const u16* la = &lds[cur][0][0];
    const u16* lb = &lds[cur][1][0];
    bf16x8 af[4], bw[4];
#pragma unroll
    for (int i = 0; i < 4; ++i)
      af[i] = *(const bf16x8*)&la[(wm * 64 + i * 16 + lr) * 32 + lg * 8];
#pragma unroll
    for (int j = 0; j < 4; ++j)
      bw[j] = *(const bf16x8*)&lb[(wn * 64 + j * 16 + lr) * 32 + lg * 8];
#pragma unroll
    for (int i = 0; i < 4; ++i)
#pragma unroll
      for (int j = 0; j < 4; ++j)
        acc[i][j] = __builtin_amdgcn_mfma_f32_16x16x32_bf16(af[i], bw[j], acc[i][j], 0, 0, 0);
    cur ^= 1;
  }

  const int m0 = bm * 128 + wm * 64;
  const int n0 = bnl * 128 + wn * 64;
#pragma unroll
  for (int i = 0; i < 4; ++i) {
#pragma unroll
    for (int j = 0; j < 4; ++j) {
      int n = n0 + j * 16 + lr;
      float bs = bias[n];
      int h_ = n >> 6, d_ = n & 63;
      if (sel == 2) {
        int m = m0 + i * 16 + lg * 4;
        int b_ = m >> 10, s_ = m & 1023;
        ushort4 o;
        o.x = f2bf(acc[i][j][0] + bs);
        o.y = f2bf(acc[i][j][1] + bs);
        o.z = f2bf(acc[i][j][2] + bs);
        o.w = f2bf(acc[i][j][3] + bs);
        *(ushort4*)&Vo[((b_ * 12 + h_) * 64 + d_) * 1024 + s_] = o;
      } else {
        u16* dst = sel == 0 ? Qo : Ko;
        float sc = sel == 0 ? QSCALE : 1.0f;
#pragma unroll
        for (int r = 0; r < 4; ++r) {
          int m = m0 + i * 16 + lg * 4 + r;
          int b_ = m >> 10, s_ = m & 1023;
          dst[((b_ * 12 + h_) * 1024 + s_) * 64 + d_] = f2bf((acc[i][j][r] + bs) * sc);
        }
      }
    }
  }
}

// ---------- O-proj GEMM: fp32 out = acc + bias + resid ----------
__global__ __launch_bounds__(256) void gemm_o(
    const u16* __restrict__ A, const u16* __restrict__ W,
    const float* __restrict__ bias, const float* __restrict__ resid,
    float* __restrict__ outf) {
  __shared__ u16 lds[2][2][128 * 32];
  const int tid = threadIdx.x;
  const int w = tid >> 6, l = tid & 63;
  const int bm = blockIdx.x, bn = blockIdx.y;
  const int lr = l & 15, lg = l >> 4;
  const int wm = w >> 1, wn = w & 1;

  const u16* Abase = A + (bm * 128) * 768;
  const u16* Wbase = W + (bn * 128) * 768;

  f32x4 acc[4][4];
#pragma unroll
  for (int i = 0; i < 4; ++i)
#pragma unroll
    for (int j = 0; j < 4; ++j) acc[i][j] = f32x4{0.f, 0.f, 0.f, 0.f};

  auto stage = [&](int buf, int k0) {
#pragma unroll
    for (int r = 0; r < 2; ++r) {
      int rowoff = r * 64 + w * 16;
      const u16* ga = Abase + (rowoff + (l >> 2)) * 768 + k0 + (l & 3) * 8;
      const u16* gw = Wbase + (rowoff + (l >> 2)) * 768 + k0 + (l & 3) * 8;
      gload_lds16(ga, &lds[buf][0][rowoff * 32]);
      gload_lds16(gw, &lds[buf][1][rowoff * 32]);
    }
  };

  stage(0, 0);
  int cur = 0;
  for (int kt = 0; kt < 24; ++kt) {
    __syncthreads();
    if (kt < 23) stage(cur ^ 1, (kt + 1) * 32);
    const u16* la = &lds[cur][0][0];
    const u16* lb = &lds[cur][1][0];
    bf16x8 af[4], bw[4];
#pragma unroll
    for (int i = 0; i < 4; ++i)
      af[i] = *(const bf16x8*)&la[(wm * 64 + i * 16 + lr) * 32 + lg * 8];
#pragma unroll
    for (int j = 0; j < 4; ++j)
      bw[j] = *(const bf16x8*)&lb[(wn * 64 + j * 16 + lr) * 32 + lg * 8];
#pragma unroll
    for (int i = 0; i < 4; ++i)
#pragma unroll
      for (int j = 0; j < 4; ++j)
        acc[i][j] = __builtin_amdgcn_mfma_f32_16x16x32_bf16(af[i], bw[j], acc[i][j], 0, 0, 0);
    cur ^= 1;
  }

  const int m0 = bm * 128 + wm * 64;
  const int n0 = bn * 128 + wn * 64;
#pragma unroll
  for (int i = 0; i < 4; ++i) {
#pragma unroll
    for (int j = 0; j < 4; ++j) {
      int n = n0 + j * 16 + lr;
      float bs = bias[n];
#pragma unroll
      for (int r = 0; r < 4; ++r) {
        int m = m0 + i * 16 + lg * 4 + r;
        outf[m * 768 + n] = acc[i][j][r] + bs + resid[m * 768 + n];
      }
    }
  }
}

// ---------- attention v3: block-cooperative LDS staging, double-buffered ----------
// grid (96, 16): blockIdx.x = bh (XCD = bh%8 keeps K/V on one XCD's L2).
// Block = 256 thr (4 waves). All 4 waves cooperatively stage K-tile [64k x 64d]
// and V-tile [64d x 64k] into LDS via global_load_lds (granule-XOR pre-swizzled
// on the GLOBAL address; LDS dest linear, per m173). One __syncthreads per
// k-tile: T3-minimum 2-phase pipeline (stage t+1 issued before computing t,
// vmcnt drained by the barrier's implicit waitcnt).
// Each wave owns 16 q-rows; no-max softmax: p = exp2(S), ones-MFMA row-sum.
__global__ __launch_bounds__(256) void attn(
    const u16* __restrict__ Q,   // [96,1024,64]
    const u16* __restrict__ Kt,  // [96,1024,64]
    const u16* __restrict__ VT,  // [96,64,1024]
    const unsigned* __restrict__ bits, // [8,1024,32]
    u16* __restrict__ ctx) {     // [8,1024,768]
  __shared__ u16 kl[2][64 * 64];      // 16 KB
  __shared__ u16 vl[2][64 * 64];      // 16 KB
  __shared__ u16 plds_all[4][16 * 64]; // 8 KB
  const int tid = threadIdx.x;
  const int w = tid >> 6, l = tid & 63;
  const int lr = l & 15, lg = l >> 4;
  const int bh = blockIdx.x;               // 0..95
  const int qt = (blockIdx.y << 2) | w;    // 0..63
  const int b_ = bh / 12, h_ = bh % 12;
  u16* plds = plds_all[w];

  const u16* Qb = Q + (bh * 1024 + qt * 16) * 64;
  const u16* Kb = Kt + bh * 1024 * 64;
  const u16* Vb = VT + bh * 64 * 1024;
  const unsigned* wb = bits + (b_ * 1024 + qt * 16) * 32;

  bf16x8 qa0 = *(const bf16x8*)&Qb[lr * 64 + lg * 8];
  bf16x8 qa1 = *(const bf16x8*)&Qb[lr * 64 + 32 + lg * 8];

  bf16x8 vones;
#pragma unroll
  for (int i = 0; i < 8; ++i) vones[i] = (__bf16)1.0f;

  f32x4 cacc[4];
#pragma unroll
  for (int j = 0; j < 4; ++j) cacc[j] = f32x4{0.f, 0.f, 0.f, 0.f};
  f32x4 lacc = f32x4{0.f, 0.f, 0.f, 0.f};

  // cooperative stage of one K-tile + one V-tile (8 KB each).
  // chunk c (0..511) covers LDS bytes [16c,16c+16) = row c>>3, granule c&7.
  // global source fetches logical granule (g ^ (row&7)) so that a reader
  // of logical granule G at row r reads physical granule G^(r&7).
  auto stage = [&](int buf, int k0) {
#pragma unroll
    for (int j = 0; j < 2; ++j) {
      const int seg = j * 4 + w;            // 1KB segment 0..7 (wave-uniform)
      const int c = seg * 64 + l;           // chunk id
      const int row = c >> 3, g = c & 7;
      const int gp = ((g ^ (row & 7)) << 3); // element offset in row
      gload_lds16(Kb + (k0 + row) * 64 + gp, &kl[buf][seg * 512]);
      gload_lds16(Vb + row * 1024 + k0 + gp, &vl[buf][seg * 512]);
    }
  };

  stage(0, 0);
  __syncthreads();   // implicit vmcnt(0) drain: tile 0 resident
  int cur = 0;

  for (int kt = 0; kt < 16; ++kt) {
    const int k0 = kt * 64;
    if (kt < 15) stage(cur ^ 1, k0 + 64);   // issue next-tile DMA first

    uint2 mm[4];
#pragma unroll
    for (int r = 0; r < 4; ++r)
      mm[r] = *(const uint2*)&wb[(lg * 4 + r) * 32 + kt * 2];

    // QK^T from LDS K-tile
    f32x4 s[4];
#pragma unroll
    for (int t = 0; t < 4; ++t) {
      const int row = t * 16 + lr;
      const int sw = row & 7;
      bf16x8 ka = *(const bf16x8*)&kl[cur][row * 64 + ((lg ^ sw) << 3)];
      bf16x8 kb2 = *(const bf16x8*)&kl[cur][row * 64 + (((4 + lg) ^ sw) << 3)];
      f32x4 z = f32x4{0.f, 0.f, 0.f, 0.f};
      z = __builtin_amdgcn_mfma_f32_16x16x32_bf16(qa0, ka, z, 0, 0, 0);
      z = __builtin_amdgcn_mfma_f32_16x16x32_bf16(qa1, kb2, z, 0, 0, 0);
      s[t] = z;
    }

    // mask + exp2 + bf16 + swizzled P-LDS write (conflict-free, verified r3)
#pragma unroll
    for (int r = 0; r < 4; ++r) {
      const int q = lg * 4 + r;
      const int sw = (q & 7) << 3;
      unsigned w0 = mm[r].x >> lr;
      unsigned w1 = mm[r].y >> lr;
#pragma unroll
      for (int t = 0; t < 4; ++t) {
        unsigned bit = (t == 0) ? (w0 & 1u)
                     : (t == 1) ? ((w0 >> 16) & 1u)
                     : (t == 2) ? (w1 & 1u)
                                : ((w1 >> 16) & 1u);
        float sv = bit ? s[t][r] : -1e30f;
        float p = exp2f(sv);
        plds[q * 64 + ((t * 16 + lr) ^ sw)] = f2bf(p);
      }
    }
    asm volatile("s_waitcnt lgkmcnt(0)" ::: "memory");
    const int swr = (lr & 7) << 3;
    bf16x8 pa0 = *(const bf16x8*)&plds[lr * 64 + ((lg * 8) ^ swr)];
    bf16x8 pa1 = *(const bf16x8*)&plds[lr * 64 + ((32 + lg * 8) ^ swr)];

    lacc = __builtin_amdgcn_mfma_f32_16x16x32_bf16(pa0, vones, lacc, 0, 0, 0);
    lacc = __builtin_amdgcn_mfma_f32_16x16x32_bf16(pa1, vones, lacc, 0, 0, 0);

    // PV from LDS V-tile
#pragma unroll
    for (int j = 0; j < 4; ++j) {
      const int row = j * 16 + lr;
      const int sw = row & 7;
      bf16x8 v0 = *(const bf16x8*)&vl[cur][row * 64 + ((lg ^ sw) << 3)];
      bf16x8 v1 = *(const bf16x8*)&vl[cur][row * 64 + (((4 + lg) ^ sw) << 3)];
      cacc[j] = __builtin_amdgcn_mfma_f32_16x16x32_bf16(pa0, v0, cacc[j], 0, 0, 0);
      cacc[j] = __builtin_amdgcn_mfma_f32_16x16x32_bf16(pa1, v1, cacc[j], 0, 0, 0);
    }

    __syncthreads();   // implicit vmcnt(0)+lgkmcnt(0): next tile resident, reads done
    cur ^= 1;
  }

  float inv[4];
#pragma unroll
  for (int r = 0; r < 4; ++r) inv[r] = 1.0f / lacc[r];
#pragma unroll
  for (int j = 0; j < 4; ++j) {
#pragma unroll
    for (int r = 0; r < 4; ++r) {
      int q = qt * 16 + lg * 4 + r;
      ctx[(b_ * 1024 + q) * 768 + h_ * 64 + j * 16 + lr] = f2bf(cacc[j][r] * inv[r]);
    }
  }
}

// ---------- LayerNorm: one wave per row of 768 ----------
__global__ __launch_bounds__(256) void layernorm(const float* __restrict__ x,
                                                 const float* __restrict__ gamma,
                                                 const float* __restrict__ beta,
                                                 float* __restrict__ out) {
  int row = blockIdx.x * 4 + (threadIdx.x >> 6);
  int l = threadIdx.x & 63;
  const float4* xr = (const float4*)(x + row * 768);
  float4 v0 = xr[l], v1 = xr[l + 64], v2 = xr[l + 128];
  float s = v0.x + v0.y + v0.z + v0.w + v1.x + v1.y + v1.z + v1.w + v2.x + v2.y + v2.z + v2.w;
#pragma unroll
  for (int d = 1; d < 64; d <<= 1) s += __shfl_xor(s, d);
  float mu = s * (1.0f / 768.0f);
  float q0, q1, q2, vs = 0.f;
  q0 = v0.x - mu; vs += q0 * q0; q0 = v0.y - mu; vs += q0 * q0;
  q0 = v0.z - mu; vs += q0 * q0; q0 = v0.w - mu; vs += q0 * q0;
  q1 = v1.x - mu; vs += q1 * q1; q1 = v1.y - mu; vs += q1 * q1;
  q1 = v1.z - mu; vs += q1 * q1; q1 = v1.w - mu; vs += q1 * q1;
  q2 = v2.x - mu; vs += q2 * q2; q2 = v2.y - mu; vs += q2 * q2;
  q2 = v2.z - mu; vs += q2 * q2; q2 = v2.w - mu; vs += q2 * q2;
#pragma unroll
  for (int d = 1; d < 64; d <<= 1) vs += __shfl_xor(vs, d);
  float rs = rsqrtf(vs * (1.0f / 768.0f) + 1e-5f);
  const float4* g4 = (const float4*)gamma;
  const float4* b4 = (const float4*)beta;
  float4 o;
  float4 g = g4[l], bb = b4[l];
  o.x = (v0.x - mu) * rs * g.x + bb.x; o.y = (v0.y - mu) * rs * g.y + bb.y;
  o.z = (v0.z - mu) * rs * g.z + bb.z; o.w = (v0.w - mu) * rs * g.w + bb.w;
  ((float4*)(out + row * 768))[l] = o;
  g = g4[l + 64]; bb = b4[l + 64];
  o.x = (v1.x - mu) * rs * g.x + bb.x; o.y = (v1.y - mu) * rs * g.y + bb.y;
  o.z = (v1.z - mu) * rs * g.z + bb.z; o.w = (v1.w - mu) * rs * g.w + bb.w;
  ((float4*)(out + row * 768))[l + 64] = o;
  g = g4[l + 128]; bb = b4[l + 128];
  o.x = (v2.x - mu) * rs * g.x + bb.x; o.y = (v2.y - mu) * rs * g.y + bb.y;
  o.z = (v2.z - mu) * rs * g.z + bb.z; o.w = (v2.w - mu) * rs * g.w + bb.w;
  ((float4*)(out + row * 768))[l + 128] = o;
}

// ---------- launch ----------
extern "C" void kernel_launch(void* const* d_in, const int* in_sizes, int n_in,
                              void* d_out, int out_size, void* d_ws, size_t ws_size,
                              hipStream_t stream) {
  (void)in_sizes; (void)n_in; (void)out_size; (void)ws_size;
  const float* inputs = (const float*)d_in[0];
  const int* adj = (const int*)d_in[1];
  const float* Wq = (const float*)d_in[2];
  const float* bq = (const float*)d_in[3];
  const float* Wk = (const float*)d_in[4];
  const float* bk = (const float*)d_in[5];
  const float* Wv = (const float*)d_in[6];
  const float* bv = (const float*)d_in[7];
  const float* Wo = (const float*)d_in[8];
  const float* bo = (const float*)d_in[9];
  const float* gamma = (const float*)d_in[10];
  const float* beta = (const float*)d_in[11];
  float* out = (float*)d_out;
  char* ws = (char*)d_ws;

  // workspace layout (bytes)
  u16* Xbf = (u16*)(ws + 0);              // 12,582,912  (ctx bf16 aliases this later)
  u16* Wqb = (u16*)(ws + 12582912);       //  4 x 1,179,648 contiguous (cvt_w4)
  u16* Wkb = (u16*)(ws + 13762560);
  u16* Wvb = (u16*)(ws + 14942208);
  u16* Wob = (u16*)(ws + 16121856);
  u16* Qb  = (u16*)(ws + 17301504);       // 12,582,912  (x fp32 aliases Q+K later)
  u16* Kb  = (u16*)(ws + 29884416);       // 12,582,912
  u16* VTb = (u16*)(ws + 42467328);       // 12,582,912
  unsigned* bits = (unsigned*)(ws + 55050240); // 1,048,576  -> total 56,098,816
  u16* ctxb = (u16*)(ws + 0);
  float* xbuf = (float*)(ws + 17301504);

  cvt_f32_bf16<<<6144, 256, 0, stream>>>(inputs, Xbf, 1572864);
  cvt_w4<<<dim3(576, 4), 256, 0, stream>>>(Wq, Wk, Wv, Wo, Wqb);
  pack_adj<<<32768, 256, 0, stream>>>(adj, bits);

  gemm_qkv<<<dim3(64, 18), 256, 0, stream>>>(Xbf, Wqb, Wkb, Wvb, bq, bk, bv, Qb, Kb, VTb);

  attn<<<dim3(96, 16), 256, 0, stream>>>(Qb, Kb, VTb, bits, ctxb);

  gemm_o<<<dim3(64, 6), 256, 0, stream>>>(ctxb, Wob, bo, inputs, xbuf);

  layernorm<<<2048, 256, 0, stream>>>(xbuf, gamma, beta, out);
}